// Round 1
// 389.164 us; speedup vs baseline: 1.0432x; 1.0432x over previous
//
#include <hip/hip_runtime.h>
#include <stdint.h>

typedef __bf16 bf16x8 __attribute__((ext_vector_type(8)));
typedef float floatx4 __attribute__((ext_vector_type(4)));

__device__ __forceinline__ void gload_lds16(const void* g, void* l) {
    __builtin_amdgcn_global_load_lds((const __attribute__((address_space(1))) void*)g,
                                     (__attribute__((address_space(3))) void*)l, 16, 0, 0);
}

__device__ __forceinline__ uint16_t f2bf(float f) {
    uint32_t u = __float_as_uint(f);
    u += 0x7fff + ((u >> 16) & 1);   // RNE
    return (uint16_t)(u >> 16);
}
__device__ __forceinline__ uint32_t f2bf2(float lo, float hi) {
    return (uint32_t)f2bf(lo) | ((uint32_t)f2bf(hi) << 16);
}

// ---- fused normalize_adj + sparse row gather ------------------------------
struct AmulSM {
    float vv[256];
    int   jj[256];
    float part[4];
    int   wcnt[4];
    int   woff[4];
    float sinv;
    int   n0;
};

__device__ __forceinline__ void amul_body(const float* __restrict__ adj,
                                          const float* __restrict__ H,
                                          uint16_t* __restrict__ outp,
                                          int b, int i, int tid, AmulSM* sm)
{
    const float* A = adj + ((size_t)b << 16);
    float aij = A[(i << 8) + tid];
    float aji = A[(tid << 8) + i];
    float v = fmaxf(aij, aji);
    if (tid == i) v += 1.0f;

    float s = v;
    #pragma unroll
    for (int off = 32; off > 0; off >>= 1) s += __shfl_down(s, off);

    bool pred = v != 0.0f;
    unsigned long long m = __ballot(pred);
    int wid = tid >> 6;
    if ((tid & 63) == 0) { sm->part[wid] = s; sm->wcnt[wid] = (int)__popcll(m); }
    __syncthreads();
    if (tid == 0) {
        float t = sm->part[0] + sm->part[1] + sm->part[2] + sm->part[3];
        sm->sinv = t > 0.0f ? 1.0f / t : 0.0f;
        int o = 0;
        #pragma unroll
        for (int w = 0; w < 4; ++w) { sm->woff[w] = o; o += sm->wcnt[w]; }
        sm->n0 = o;
    }
    __syncthreads();
    if (pred) {
        int pos = sm->woff[wid] + (int)__popcll(m & ((1ull << (tid & 63)) - 1ull));
        sm->vv[pos] = v * sm->sinv;
        sm->jj[pos] = tid;
    }
    __syncthreads();

    const int n0 = sm->n0;
    const int f0 = tid * 8;
    const float* Hb = H + (((size_t)b) << 8) * 2048;
    float acc[8] = {};
    for (int c = 0; c < n0; ++c) {
        float av = sm->vv[c];
        const float* hp = Hb + (size_t)sm->jj[c] * 2048 + f0;
        float4 p = *(const float4*)hp;
        float4 q = *(const float4*)(hp + 4);
        acc[0] += av * p.x; acc[1] += av * p.y; acc[2] += av * p.z; acc[3] += av * p.w;
        acc[4] += av * q.x; acc[5] += av * q.y; acc[6] += av * q.z; acc[7] += av * q.w;
    }
    uint4 o;
    o.x = f2bf2(acc[0], acc[1]);
    o.y = f2bf2(acc[2], acc[3]);
    o.z = f2bf2(acc[4], acc[5]);
    o.w = f2bf2(acc[6], acc[7]);
    *(uint4*)(outp + (((size_t)b << 8) + i) * 2048 + f0) = o;
}

// XCD-swizzled (b,i): XCD x (=bid%8) keeps one batch's H (2MB) L2-resident
__device__ __forceinline__ void amul_swizzle(int bid, int& b, int& i) {
    int x = bid & 7, g = bid >> 3;
    b = x >> 1;
    i = ((x & 1) << 7) + g;
}

// ---- dispatch 1: amul#1 | wT | W1/W2-transpose | pad_x (inputs only) ------
//   [0, 1024)        amul#1: gbf = a @ nodes (bf16)
//   [1024, 3072)     conv_w -> wT bf16
//   [3072, 5120)     W1/W2 -> bf16 transpose
//   [5120, 17456)    pad_x (float4, 12336 blocks)
#define PR_AM 1024
#define PR_W  3072
#define PR_T  5120
#define PR_N  17456

__global__ __launch_bounds__(256)
void k_prep(const float* __restrict__ x, uint16_t* __restrict__ xpad,
            const float* __restrict__ w, uint16_t* __restrict__ wT,
            const float* __restrict__ W1, const float* __restrict__ W2,
            uint16_t* __restrict__ W1T, uint16_t* __restrict__ W2T,
            const float* __restrict__ adj, const float* __restrict__ nodes,
            uint16_t* __restrict__ gbf)
{
    __shared__ union {
        float  wbuf[6144];
        float  tile[64][65];
        AmulSM am;
    } sm;
    const int bid = blockIdx.x;
    const int tid = threadIdx.x;

    if (bid < PR_AM) {
        int b, i; amul_swizzle(bid, b, i);
        amul_body(adj, nodes, gbf, b, i, tid, &sm.am);
    } else if (bid < PR_W) {
        // conv_w [o][i][h] -> wT [o][h*2048+i] bf16 (LDS-staged)
        int o = bid - PR_AM;
        const float* src = w + (size_t)o * 6144;
        uint16_t*    dst = wT + (size_t)o * 6144;
        #pragma unroll
        for (int it = 0; it < 24; ++it)
            sm.wbuf[it * 256 + tid] = src[it * 256 + tid];
        __syncthreads();
        #pragma unroll
        for (int h = 0; h < 3; ++h)
            #pragma unroll
            for (int c = 0; c < 8; ++c) {
                int i = c * 256 + tid;
                dst[h * 2048 + i] = f2bf(sm.wbuf[i * 3 + h]);   // stride-3: conflict-free
            }
    } else if (bid < PR_T) {
        // W1/W2 [2048][2048] -> bf16 transpose
        int t  = bid - PR_W;
        int z  = t >> 10;
        int by = (t >> 5) & 31;
        int bx = t & 31;
        const float* src = z ? W2 : W1;
        uint16_t*    dst = z ? W2T : W1T;
        int tx = tid & 63, ty = tid >> 6;
        for (int rr = ty; rr < 64; rr += 4)
            sm.tile[rr][tx] = src[(size_t)(by * 64 + rr) * 2048 + bx * 64 + tx];
        __syncthreads();
        for (int rr = ty; rr < 64; rr += 4)
            dst[(size_t)(bx * 64 + rr) * 2048 + by * 64 + tx] = f2bf(sm.tile[tx][rr]);
    } else {
        // x [12,512,2048] f32 -> xpad [12,514,2048] bf16, 4 elems/thread
        int idx4 = (bid - PR_T) * 256 + tid;       // < 3,158,016
        int ch4  = idx4 & 511;
        int tmp  = idx4 >> 9;                      // b*514 + tt
        int b    = tmp / 514;
        int tt   = tmp - b * 514;
        float4 v = {0.0f, 0.0f, 0.0f, 0.0f};
        if (tt >= 1 && tt <= 512)
            v = *(const float4*)(x + ((size_t)(b * 512 + tt - 1) << 11) + ch4 * 4);
        uint2 o = { f2bf2(v.x, v.y), f2bf2(v.z, v.w) };
        ((uint2*)xpad)[idx4] = o;
    }
}

// ---- 64x64 GEMM tile body, BK=64, LDS split-half layout [s][64][32] -------
// As/Bs each 4096 u16. Staging: 2 passes/matrix, pass p fills half s=p
// (all 64 rows, cols p*32..p*32+31); LDS dest = p*2048 + tid*8 (contiguous).
template<bool RELU>
__device__ __forceinline__ void g64_tile(uint16_t* As, uint16_t* Bs,
                                         const uint16_t* __restrict__ A,
                                         const uint16_t* __restrict__ BT,
                                         float* __restrict__ C, const float* __restrict__ bias,
                                         int rt, int ct, int tid)
{
    const int lane = tid & 63;
    const int wave = tid >> 6;
    const int wm   = (wave >> 1) * 32;
    const int wn   = (wave & 1) * 32;
    const int lm   = lane & 15;
    const int kq   = (lane >> 4) * 8;
    const int sr   = tid >> 2;           // 0..63 (row)
    const int sc   = (tid & 3) * 8;      // 0..24 (col within half)

    const size_t abase = (size_t)(rt + sr) * 2048 + sc;
    const size_t bbase = (size_t)(ct + sr) * 2048 + sc;

    floatx4 acc[2][2] = {};

    for (int k0 = 0; k0 < 2048; k0 += 64) {
        #pragma unroll
        for (int p = 0; p < 2; ++p) {
            gload_lds16(A  + abase + k0 + p * 32, &As[p * 2048 + tid * 8]);
            gload_lds16(BT + bbase + k0 + p * 32, &Bs[p * 2048 + tid * 8]);
        }
        __syncthreads();

        #pragma unroll
        for (int s = 0; s < 2; ++s) {
            bf16x8 af[2], bfr[2];
            #pragma unroll
            for (int mt = 0; mt < 2; ++mt)
                af[mt] = *(const bf16x8*)&As[s * 2048 + (wm + mt * 16 + lm) * 32 + kq];
            #pragma unroll
            for (int nt = 0; nt < 2; ++nt)
                bfr[nt] = *(const bf16x8*)&Bs[s * 2048 + (wn + nt * 16 + lm) * 32 + kq];
            #pragma unroll
            for (int mt = 0; mt < 2; ++mt)
                #pragma unroll
                for (int nt = 0; nt < 2; ++nt)
                    acc[mt][nt] = __builtin_amdgcn_mfma_f32_16x16x32_bf16(af[mt], bfr[nt], acc[mt][nt], 0, 0, 0);
        }
        __syncthreads();
    }

    const int lq = lane >> 4;
    #pragma unroll
    for (int mt = 0; mt < 2; ++mt)
        #pragma unroll
        for (int nt = 0; nt < 2; ++nt) {
            int col = ct + wn + nt * 16 + lm;
            float bv = bias[col];
            #pragma unroll
            for (int r = 0; r < 4; ++r) {
                int row = rt + wm + mt * 16 + lq * 4 + r;
                float v = acc[mt][nt][r] + bv;
                if (RELU) v = fmaxf(v, 0.0f);
                C[(size_t)row * 2048 + col] = v;
            }
        }
}

// ===========================================================================
// conv GEMM, 8-phase-class pipelined schedule (T2 swizzle + T3/T4 counted
// vmcnt + T5 setprio), tile 192x256, BK=32, 4-deep LDS buffering.
//   M=6144 rows (im2col: addr = rowbase + k), N=2048, K=6144 (192 K-tiles)
//   512 threads = 8 waves (2M x 4N), per-wave C = 96x64 (acc[6][4])
//   LDS: A 4x12288 B @ 0, B 4x16384 B @ 49152  -> 114688 B total
//   Swizzle (both sides): phys = (row<<6) | ((colbyte) ^ ((row&3)<<4))
//   Per K-tile window: 2 phases; counted vmcnt(6) once per window (never 0).
// ===========================================================================
template<int BUF, bool STG, int VN>
__device__ __forceinline__ void conv_win(char* ldsb, int tid,
    const uint16_t*& aS0, const uint16_t*& aS1,
    const uint16_t*& bS0, const uint16_t*& bS1,
    int aoff, int boff, floatx4 (&acc)[6][4])
{
    char* As  = ldsb + BUF * 12288;
    char* Bs  = ldsb + 49152 + BUF * 16384;
    constexpr int NB = (BUF + 3) & 3;
    char* As3 = ldsb + NB * 12288;
    char* Bs3 = ldsb + 49152 + NB * 16384;

    bf16x8 av[3], bv[4];
    // ---------------- phase A (h=0): rows mw*96 + 0..47 --------------------
    #pragma unroll
    for (int j = 0; j < 3; ++j) av[j] = *(const bf16x8*)(As + aoff + j * 1024);
    #pragma unroll
    for (int j = 0; j < 4; ++j) bv[j] = *(const bf16x8*)(Bs + boff + j * 1024);
    if constexpr (STG) {
        gload_lds16(aS0, As3 + tid * 16); aS0 += 32;
        if (tid < 256) { gload_lds16(aS1, As3 + 8192 + tid * 16); aS1 += 32; }
    }
    __builtin_amdgcn_s_barrier();
    asm volatile("s_waitcnt lgkmcnt(0)");
    __builtin_amdgcn_s_setprio(1);
    #pragma unroll
    for (int jm = 0; jm < 3; ++jm)
        #pragma unroll
        for (int fn = 0; fn < 4; ++fn)
            acc[jm][fn] = __builtin_amdgcn_mfma_f32_16x16x32_bf16(av[jm], bv[fn], acc[jm][fn], 0, 0, 0);
    __builtin_amdgcn_s_setprio(0);
    __builtin_amdgcn_s_barrier();
    // ---------------- phase B (h=1): rows mw*96 + 48..95 -------------------
    #pragma unroll
    for (int j = 0; j < 3; ++j) av[j] = *(const bf16x8*)(As + aoff + 3072 + j * 1024);
    if constexpr (STG) {
        gload_lds16(bS0, Bs3 + tid * 16); bS0 += 32;
        gload_lds16(bS1, Bs3 + 8192 + tid * 16); bS1 += 32;
    }
    if constexpr (VN >= 0) asm volatile("s_waitcnt vmcnt(%0)" :: "i"(VN));
    __builtin_amdgcn_s_barrier();
    asm volatile("s_waitcnt lgkmcnt(0)");
    __builtin_amdgcn_s_setprio(1);
    #pragma unroll
    for (int jm = 0; jm < 3; ++jm)
        #pragma unroll
        for (int fn = 0; fn < 4; ++fn)
            acc[3 + jm][fn] = __builtin_amdgcn_mfma_f32_16x16x32_bf16(av[jm], bv[fn], acc[3 + jm][fn], 0, 0, 0);
    __builtin_amdgcn_s_setprio(0);
    __builtin_amdgcn_s_barrier();
}

// ---- dispatch 2: conv GEMM (256 blocks, all CUs) then gemm64#1 (256) ------
__global__ __launch_bounds__(512, 2)
void k_big(const uint16_t* __restrict__ xpad, const uint16_t* __restrict__ wmT,
           float* __restrict__ feats, const float* __restrict__ conv_b,
           const uint16_t* __restrict__ gbf, const uint16_t* __restrict__ W1T,
           float* __restrict__ h, const float* __restrict__ b1)
{
    __shared__ __align__(16) char smem[114688];
    const int bid = blockIdx.x;
    const int tid = threadIdx.x;

    if (bid < 256) {
        // -------- conv: 192x256 tile, XCD-swizzled (256 % 8 == 0) ----------
        const int xcd  = bid & 7;
        const int gg   = bid >> 3;                 // 0..31
        const int tile = xcd * 32 + gg;
        const int rt   = (tile >> 3) * 192;        // 0..5952
        const int ct   = (tile & 7) * 256;         // 0..1792

        const int lane = tid & 63, wave = tid >> 6;
        const int mw = wave >> 2, nw = wave & 3;
        const int lm = lane & 15;
        const int kq2 = (lane >> 4) * 16;                 // byte k-offset
        const int xc  = kq2 ^ ((lm & 3) << 4);            // read-side swizzle
        const int aoff = ((mw * 96 + lm) << 6) + xc;
        const int boff = ((nw * 64 + lm) << 6) + xc;

        // staging constants: chunk c -> (row = c>>2, kcol = ((c&3)^(row&3))*8)
        const int c1  = 512 + tid;
        const int r0  = tid >> 2,  kc0 = ((tid & 3) ^ (r0 & 3)) * 8;
        const int r1  = c1 >> 2,   kc1 = ((c1 & 3) ^ (r1 & 3)) * 8;

        const int RA0 = rt + r0;
        const int RA1 = rt + r1;   // only dereferenced when tid<256 (r1<192)
        const uint16_t* aS0 = xpad + (((size_t)((RA0 >> 9) * 514 + (RA0 & 511))) << 11) + kc0;
        const uint16_t* aS1 = xpad + (((size_t)((RA1 >> 9) * 514 + (RA1 & 511))) << 11) + kc1;
        const uint16_t* bS0 = wmT + (size_t)(ct + r0) * 6144 + kc0;
        const uint16_t* bS1 = wmT + (size_t)(ct + r1) * 6144 + kc1;

        // prologue: stage K-tiles 0,1,2 (counted: keep 6 loads in flight)
        #pragma unroll
        for (int p = 0; p < 3; ++p) {
            char* As3 = smem + p * 12288;
            char* Bs3 = smem + 49152 + p * 16384;
            gload_lds16(aS0, As3 + tid * 16); aS0 += 32;
            if (tid < 256) { gload_lds16(aS1, As3 + 8192 + tid * 16); aS1 += 32; }
            gload_lds16(bS0, Bs3 + tid * 16); bS0 += 32;
            gload_lds16(bS1, Bs3 + 8192 + tid * 16); bS1 += 32;
        }
        asm volatile("s_waitcnt vmcnt(6)");   // tile 0 landed; 1,2 in flight
        __builtin_amdgcn_s_barrier();

        floatx4 acc[6][4] = {};
        // windows 0..187 (stage tiles 3..190), vmcnt(6) once per window
        #pragma unroll 1
        for (int it = 0; it < 47; ++it) {
            conv_win<0, true, 6>(smem, tid, aS0, aS1, bS0, bS1, aoff, boff, acc);
            conv_win<1, true, 6>(smem, tid, aS0, aS1, bS0, bS1, aoff, boff, acc);
            conv_win<2, true, 6>(smem, tid, aS0, aS1, bS0, bS1, aoff, boff, acc);
            conv_win<3, true, 6>(smem, tid, aS0, aS1, bS0, bS1, aoff, boff, acc);
        }
        // epilogue: w=188 stages tile 191; then drain 6 -> 3 -> 0
        conv_win<0, true,  6>(smem, tid, aS0, aS1, bS0, bS1, aoff, boff, acc);
        conv_win<1, false, 3>(smem, tid, aS0, aS1, bS0, bS1, aoff, boff, acc);
        conv_win<2, false, 0>(smem, tid, aS0, aS1, bS0, bS1, aoff, boff, acc);
        conv_win<3, false,-1>(smem, tid, aS0, aS1, bS0, bS1, aoff, boff, acc);

        // C write: 16x16 frag layout col=lane&15, row=(lane>>4)*4+r
        const int lq = lane >> 4;
        #pragma unroll
        for (int fm = 0; fm < 6; ++fm)
            #pragma unroll
            for (int fn = 0; fn < 4; ++fn) {
                int col = ct + nw * 64 + fn * 16 + lm;
                float bb = conv_b[col];
                #pragma unroll
                for (int r = 0; r < 4; ++r) {
                    int row = rt + mw * 96 + fm * 16 + lq * 4 + r;
                    feats[(size_t)row * 2048 + col] = fmaxf(acc[fm][fn][r] + bb, 0.0f);
                }
            }
    } else {
        // -------- gemm64#1: h = relu(gbf @ W1T^T + b1), 2 tiles/block ------
        const int t    = bid - 256;            // 0..255
        const int half = tid >> 8;
        const int st   = t * 2 + half;         // 0..511
        const int rt   = (st & 15) * 64;       // M=1024
        const int ct   = (st >> 4) * 64;       // N=2048
        uint16_t* As = (uint16_t*)smem + half * 8192;   // 16 KB per half
        g64_tile<true>(As, As + 4096, gbf, W1T, h, b1, rt, ct, tid & 255);
    }
}

// ---- dispatch 3: ahb = a @ h (bf16), normalize folded in, XCD-swizzled ----
__global__ __launch_bounds__(256)
void k_amul(const float* __restrict__ adj, const float* __restrict__ H,
            uint16_t* __restrict__ outp)
{
    __shared__ AmulSM sm;
    int b, i; amul_swizzle(blockIdx.x, b, i);
    amul_body(adj, H, outp, b, i, threadIdx.x, &sm);
}

// ---- dispatch 4: out = ahb @ W2T^T + b2, BK=64, XCD-swizzled --------------
__global__ __launch_bounds__(256)
void k_gemm64(const uint16_t* __restrict__ A, const uint16_t* __restrict__ BT,
              float* __restrict__ C, const float* __restrict__ bias)
{
    __shared__ __align__(16) uint16_t lds[8192];
    const int bid = blockIdx.x;
    const int xc  = bid & 7;
    const int g   = bid >> 3;
    const int rt  = (g & 15) * 64;
    const int ct  = (4 * xc + (g >> 4)) * 64;
    g64_tile<false>(lds, lds + 4096, A, BT, C, bias, rt, ct, threadIdx.x);
}

// ---- launch ---------------------------------------------------------------

extern "C" void kernel_launch(void* const* d_in, const int* in_sizes, int n_in,
                              void* d_out, int out_size, void* d_ws, size_t ws_size,
                              hipStream_t stream)
{
    const float* x      = (const float*)d_in[0];
    const float* nodes  = (const float*)d_in[1];
    const float* adj    = (const float*)d_in[2];
    const float* conv_w = (const float*)d_in[3];
    const float* conv_b = (const float*)d_in[4];
    const float* W1     = (const float*)d_in[5];
    const float* b1     = (const float*)d_in[6];
    const float* W2     = (const float*)d_in[7];
    const float* b2     = (const float*)d_in[8];
    float* out = (float*)d_out;

    char* ws = (char*)d_ws;
    uint16_t* xpad   = (uint16_t*)(ws);                 // 25,288,704
    uint16_t* wmT    = (uint16_t*)(ws + 25288704);      // 25,165,824
    uint16_t* W1T    = (uint16_t*)(ws + 50454528);      // 8,388,608
    uint16_t* W2T    = (uint16_t*)(ws + 58843136);      // 8,388,608
    uint16_t* gbf    = (uint16_t*)(ws + 67231744);      // 4,194,304  a@nodes (bf16)
    float*    h      = (float*)   (ws + 71426048);      // 8,388,608  relu(gbf@W1+b1)
    uint16_t* ahb    = (uint16_t*)(ws + 79814656);      // 4,194,304  a@h (bf16)

    // d1: everything that depends only on inputs
    k_prep<<<PR_N, 256, 0, stream>>>(x, xpad, conv_w, wmT,
                                     W1, W2, W1T, W2T, adj, nodes, gbf);
    // d2: conv GEMM (pipelined 192x256) then gemm64#1 in tail shadow
    k_big<<<512, 512, 0, stream>>>(xpad, wmT, out, conv_b, gbf, W1T, h, b1);
    // d3: ahb = a @ h
    k_amul<<<1024, 256, 0, stream>>>(adj, h, ahb);
    // d4: out_gcn = ahb @ W2 + b2
    k_gemm64<<<512, 256, 0, stream>>>(ahb, W2T, out + 12582912, b2);
}